// Round 5
// baseline (12086.417 us; speedup 1.0000x reference)
//
#include <hip/hip_runtime.h>
#include <hip/hip_bf16.h>
#include <cstdint>

// ---------------------------------------------------------------------------
// Seq2Seq (B=64, S=128, T=64, V=10000, E=128, H=256).
// ALL float tensors are FLOAT32 (per reference, jnp.float32) — inputs read as
// const float*, d_out written as float*. MFMA compute in bf16 via one-time
// per-launch weight conversion into a module-global bf16 pool.
// Encoder: 2-layer biLSTM (persistent kernels, Whh register-stationary).
// Decoder: 63 steps of attention + LSTMCell + V-projection.
// ---------------------------------------------------------------------------

typedef __hip_bfloat16 bf16;
typedef __attribute__((ext_vector_type(8))) short short8;   // 8 bf16 = 4 VGPRs
typedef __attribute__((ext_vector_type(4))) float f32x4;

// ---- bf16 weight pool offsets (elements) ----------------------------------
#define OFF_E1F_WIH 0L
#define OFF_E1B_WIH 131072L
#define OFF_E2F_WIH 262144L
#define OFF_E2B_WIH 786432L
#define OFF_E1F_WHH 1310720L
#define OFF_E1B_WHH 1572864L
#define OFF_E2F_WHH 1835008L
#define OFF_E2B_WHH 2097152L
#define OFF_DWIH    2359296L
#define OFF_WFC     3014656L
#define OFF_WA      10694656L
#define WBF_TOTAL   10891264L

// ---- module-scope scratch (allocated at .so load) -------------------------
__device__ __align__(16) bf16     g_WBF[WBF_TOTAL];     // 21.8 MB bf16 weights
__device__ __align__(16) float    g_X1F[8192 * 1024];   // 32 MB gate preacts fwd
__device__ __align__(16) float    g_X1B[8192 * 1024];   // 32 MB gate preacts bwd
__device__ __align__(16) bf16     g_EMB[8192 * 128];    // 2 MB embedded src
__device__ __align__(16) bf16     g_OUT1[8192 * 512];   // 8 MB layer-1 output
__device__ __align__(16) bf16     g_ENC[8192 * 512];    // 8 MB encoder output
__device__ __align__(16) float    g_EWA[8192 * 256];    // 8 MB enc@Wa[:,H:]^T
__device__ __align__(16) float    g_HID[64 * 256];      // decoder hidden (f32)
__device__ __align__(16) bf16     g_XIN[64 * 640];      // [emb|ctx]
__device__ __align__(16) bf16     g_HC[64 * 768];       // [h|ctx]
__device__ __align__(16) unsigned g_HG32[2 * 2 * 64 * 256]; // h exchange (f32 bits)
__device__ int g_FLG[64];                               // sync flags (2 layers)

__device__ __forceinline__ float b2f(bf16 x) { return __bfloat162float(x); }
__device__ __forceinline__ float fexp2(float x) { return __builtin_amdgcn_exp2f(x); }
__device__ __forceinline__ float frcp(float x)  { return __builtin_amdgcn_rcpf(x); }
__device__ __forceinline__ float clampf(float x, float L) {
  return fminf(fmaxf(x, -L), L);       // NaN -> -L
}
__device__ __forceinline__ float sigf(float x) {
  x = clampf(x, 30.f);
  return frcp(1.f + fexp2(-1.44269504f * x));
}
__device__ __forceinline__ float tanh_f(float x) {
  x = clampf(x, 15.f);
  float e = fexp2(2.885390082f * x);          // e^(2x)
  return (e - 1.f) * frcp(e + 1.f);
}
__device__ __forceinline__ f32x4 mfma16(short8 a, short8 b, f32x4 c) {
  return __builtin_amdgcn_mfma_f32_16x16x32_bf16(a, b, c, 0, 0, 0);
}

// ---------------------------------------------------------------------------
__global__ __launch_bounds__(64) void zero_flags() { g_FLG[threadIdx.x] = 0; }

// f32 -> bf16 weight conversion into pool (n multiple of 4)
__global__ __launch_bounds__(256) void cvt_w(const float* __restrict__ src,
                                             long off, int n) {
  int i = (blockIdx.x * 256 + threadIdx.x) * 4;
  if (i >= n) return;
  float4 v = *(const float4*)(src + i);
  bf16* d = g_WBF + off + i;
  d[0] = __float2bfloat16(v.x);
  d[1] = __float2bfloat16(v.y);
  d[2] = __float2bfloat16(v.z);
  d[3] = __float2bfloat16(v.w);
}

// emb[b*S+s][e] = enc_emb[src[b][s]][e]  (f32 table -> bf16)
__global__ __launch_bounds__(256) void embed_k(const int* __restrict__ src,
                                               const float* __restrict__ tab) {
  int i4 = (blockIdx.x * 256 + threadIdx.x) * 4;      // 8192*128 elems
  int row = i4 >> 7, e = i4 & 127;
  int tok = src[row];
  if (tok < 0 || tok >= 10000) tok = 0;               // defensive
  float4 v = *(const float4*)&tab[(size_t)tok * 128 + e];
  bf16* d = &g_EMB[(size_t)row * 128 + e];
  d[0] = __float2bfloat16(v.x);
  d[1] = __float2bfloat16(v.y);
  d[2] = __float2bfloat16(v.z);
  d[3] = __float2bfloat16(v.w);
}

// ---------------------------------------------------------------------------
// C[M,N] = A[M,K] @ W[N,K]^T + bias(f32).  Writes f32 (Cf), clamped.
// grid = (M/64, ceil(N/64)); block 256 = 4 waves; wave w: rows [bx*64+16w,+16).
__device__ __forceinline__ void gemm_core(const bf16* __restrict__ A, int lda,
                                          const bf16* __restrict__ W, int ldw, int wcol,
                                          const float* __restrict__ bias,
                                          float* __restrict__ Cf,
                                          long ldc, int N, int K, float clampL) {
  const int wave = threadIdx.x >> 6, lane = threadIdx.x & 63;
  const int l15 = lane & 15, quad = lane >> 4;
  const int m0 = blockIdx.x * 64 + wave * 16;
  const int n0 = blockIdx.y * 64;

  f32x4 acc[4];
#pragma unroll
  for (int j = 0; j < 4; ++j) acc[j] = (f32x4){0.f, 0.f, 0.f, 0.f};

  const bf16* Arow = A + (size_t)(m0 + l15) * lda + quad * 8;
  for (int k = 0; k < K; k += 32) {
    short8 a = *(const short8*)(Arow + k);
#pragma unroll
    for (int j = 0; j < 4; ++j) {
      int n = n0 + 16 * j + l15;
      short8 bfr = (short8){0, 0, 0, 0, 0, 0, 0, 0};
      if (n < N) bfr = *(const short8*)(W + (size_t)n * ldw + wcol + k + quad * 8);
      acc[j] = mfma16(a, bfr, acc[j]);
    }
  }
#pragma unroll
  for (int j = 0; j < 4; ++j) {
    int n = n0 + 16 * j + l15;
    if (n >= N) continue;
    float bv = bias ? bias[n] : 0.f;
#pragma unroll
    for (int r = 0; r < 4; ++r) {
      int m = m0 + quad * 4 + r;
      Cf[(size_t)m * ldc + n] = clampf(acc[j][r] + bv, clampL);
    }
  }
}

// layer-1 input GEMM: g_EMB[8192,128] @ W[1024,128]^T -> g_X1F/g_X1B (f32)
__global__ __launch_bounds__(256) void gemm_x1(long offW, const float* __restrict__ bias,
                                               int bwd) {
  gemm_core(g_EMB, 128, g_WBF + offW, 128, 0, bias, bwd ? g_X1B : g_X1F,
            1024, 1024, 128, 64.f);
}
// layer-2 input GEMM: g_OUT1[8192,512] @ W[1024,512]^T -> g_X1F/g_X1B (reuse)
__global__ __launch_bounds__(256) void gemm_x2(long offW, const float* __restrict__ bias,
                                               int bwd) {
  gemm_core(g_OUT1, 512, g_WBF + offW, 512, 0, bias, bwd ? g_X1B : g_X1F,
            1024, 1024, 512, 64.f);
}
// attention precompute: g_ENC[8192,512] @ Wa[:,256:768]^T -> g_EWA (f32)
__global__ __launch_bounds__(256) void gemm_ewa() {
  gemm_core(g_ENC, 512, g_WBF + OFF_WA, 768, 256, nullptr, g_EWA, 256, 256, 512, 64.f);
}
// prediction: g_HC[64,768] @ Wfc[10000,768]^T + bfc -> outp+step*10000 (f32)
__global__ __launch_bounds__(256) void gemm_pred(const float* __restrict__ bfc,
                                                 float* __restrict__ outp, int step) {
  gemm_core(g_HC, 768, g_WBF + OFF_WFC, 768, 0, bfc, outp + (size_t)step * 10000,
            640000, 10000, 768, 512.f);
}

// ---------------------------------------------------------------------------
// Persistent biLSTM layer. grid = 16: dir d = bx>>3, slice m = bx&7 (u0=32m).
// Whh fragments stationary in registers (wave = gate), h in LDS, per-step
// h-slice exchange via g_HG32 (parity double-buffered, agent-scope relaxed
// atomics for data, release/acquire flags for ordering, capped spins).
__global__ __launch_bounds__(256) void lstm_layer(long offWhf, long offWhb, int layer) {
  const int bx = blockIdx.x;
  const int d = bx >> 3, m = bx & 7;
  const int u0 = m * 32;
  const float* __restrict__ X  = d ? g_X1B : g_X1F;
  const bf16*  __restrict__ Wh = g_WBF + (d ? offWhb : offWhf);
  bf16* __restrict__ out = layer ? g_ENC : g_OUT1;     // [64][128][512]
  int*  __restrict__ flags = g_FLG + layer * 16;

  __shared__ __align__(16) bf16 hlds[64 * 264];   // h state, pitch 264
  __shared__ float gst[64 * 132];                 // h-part gate staging (f32)

  const int tid = threadIdx.x;
  const int wave = tid >> 6, lane = tid & 63, l15 = lane & 15, quad = lane >> 4;

  // Stationary B frags: gate = wave; rows grow = wave*256 + u0 + 16*nt + l15.
  short8 bfrag[2][8];
#pragma unroll
  for (int nt = 0; nt < 2; ++nt) {
    int grow = wave * 256 + u0 + 16 * nt + l15;
#pragma unroll
    for (int kt = 0; kt < 8; ++kt)
      bfrag[nt][kt] = *(const short8*)(Wh + (size_t)grow * 256 + kt * 32 + quad * 8);
  }
  for (int i = tid; i < 64 * 264; i += 256) hlds[i] = __float2bfloat16(0.f);
  float creg[8];
#pragma unroll
  for (int i = 0; i < 8; ++i) creg[i] = 0.f;
  __syncthreads();

  for (int t = 0; t < 128; ++t) {
    const int s = d ? (127 - t) : t;
    f32x4 acc[4][2];
#pragma unroll
    for (int mt = 0; mt < 4; ++mt) {
      acc[mt][0] = (f32x4){0.f, 0.f, 0.f, 0.f};
      acc[mt][1] = (f32x4){0.f, 0.f, 0.f, 0.f};
    }
#pragma unroll
    for (int kt = 0; kt < 8; ++kt) {
      const int koff = kt * 32 + quad * 8;
#pragma unroll
      for (int mt = 0; mt < 4; ++mt) {
        short8 a = *(const short8*)&hlds[(16 * mt + l15) * 264 + koff];
        acc[mt][0] = mfma16(a, bfrag[0][kt], acc[mt][0]);
        acc[mt][1] = mfma16(a, bfrag[1][kt], acc[mt][1]);
      }
    }
#pragma unroll
    for (int mt = 0; mt < 4; ++mt)
#pragma unroll
      for (int nt = 0; nt < 2; ++nt)
#pragma unroll
        for (int r = 0; r < 4; ++r)
          gst[(16 * mt + quad * 4 + r) * 132 + wave * 32 + 16 * nt + l15] =
              clampf(acc[mt][nt][r], 64.f);
    __syncthreads();

    // epilogue: 2048 (b,uu) pairs, 8/thread; c state in registers
    unsigned* hgw = g_HG32 + ((size_t)(t & 1) * 2 + d) * 64 * 256;
#pragma unroll
    for (int i = 0; i < 8; ++i) {
      int p = tid + 256 * i;
      int b = p >> 5, uu = p & 31;
      size_t xr = ((size_t)b * 128 + s) * 1024 + u0 + uu;
      float gi = gst[b * 132 + 0  + uu] + X[xr];
      float gf = gst[b * 132 + 32 + uu] + X[xr + 256];
      float gg = gst[b * 132 + 64 + uu] + X[xr + 512];
      float go = gst[b * 132 + 96 + uu] + X[xr + 768];
      float c = clampf(sigf(gf) * creg[i] + sigf(gi) * tanh_f(gg), 256.f);
      creg[i] = c;
      float h = clampf(sigf(go) * tanh_f(c), 4.f);
      out[((size_t)b * 128 + s) * 512 + d * 256 + u0 + uu] = __float2bfloat16(h);
      if (layer == 1 && d == 0 && t == 127)
        g_HID[b * 256 + u0 + uu] = h;              // decoder hidden0, exact f32
      __hip_atomic_store(&hgw[b * 256 + u0 + uu], __float_as_uint(h),
                         __ATOMIC_RELAXED, __HIP_MEMORY_SCOPE_AGENT);
    }
    __threadfence();
    __syncthreads();
    if (tid == 0)
      __hip_atomic_store(&flags[d * 8 + m], t + 1, __ATOMIC_RELEASE, __HIP_MEMORY_SCOPE_AGENT);
    if (tid < 8) {
      for (int it = 0; it < (1 << 24); ++it) {
        if (__hip_atomic_load(&flags[d * 8 + tid], __ATOMIC_ACQUIRE,
                              __HIP_MEMORY_SCOPE_AGENT) >= t + 1) break;
        __builtin_amdgcn_s_sleep(2);
      }
    }
    __syncthreads();
    const unsigned* srcp = g_HG32 + ((size_t)(t & 1) * 2 + d) * 64 * 256;
    for (int idx = tid; idx < 64 * 256; idx += 256) {
      float hf = __uint_as_float(__hip_atomic_load(&srcp[idx], __ATOMIC_RELAXED,
                                                   __HIP_MEMORY_SCOPE_AGENT));
      hlds[(idx >> 8) * 264 + (idx & 255)] = __float2bfloat16(hf);
    }
    __syncthreads();
  }
}

// ---------------------------------------------------------------------------
// Per decoder step: token select (+argmax of prev pred), hWa, energies,
// softmax, context; writes g_XIN=[emb|ctx] and g_HC[256:768]=ctx. grid=64 (b).
__global__ __launch_bounds__(256) void attn_step(int step,
                                                 const int* __restrict__ trg,
                                                 const unsigned char* __restrict__ tfm,
                                                 const float* __restrict__ dec_emb,
                                                 const float* __restrict__ Wa,  // [256][768] f32
                                                 const float* __restrict__ ba,
                                                 const float* __restrict__ vv,
                                                 const float* __restrict__ outp) // d_out f32
{
  int b = blockIdx.x, tid = threadIdx.x;
  __shared__ float sh[256], hb[256], vsh[256], es[128], red[256];
  __shared__ int ridx[256];
  __shared__ int stok;

  if (step == 1) {
    if (tid == 0) stok = trg[b * 64];
  } else {
    const float* pr = outp + (size_t)b * 640000 + (size_t)(step - 1) * 10000;
    float bv = -3.4e38f; int bi = 0;
    for (int v2 = tid; v2 < 10000; v2 += 256) {
      float pv = pr[v2];
      if (pv > bv) { bv = pv; bi = v2; }   // ascending scan: first-max kept
    }
    red[tid] = bv; ridx[tid] = bi;
    __syncthreads();
    for (int off = 128; off; off >>= 1) {
      if (tid < off) {
        float ov = red[tid + off]; int oi = ridx[tid + off];
        if (ov > red[tid] || (ov == red[tid] && oi < ridx[tid])) { red[tid] = ov; ridx[tid] = oi; }
      }
      __syncthreads();
    }
    if (tid == 0) {
      int k = step - 1;
      // true under both uint8-bool and int32-bool storage (mask is all-True)
      int tf = (int)tfm[k] | (int)tfm[4 * k];
      int tok = tf ? trg[b * 64 + k] : ridx[0];
      if (tok < 0 || tok >= 10000) tok = 0;            // defensive
      stok = tok;
    }
    __syncthreads();
  }

  sh[tid]  = g_HID[b * 256 + tid];
  vsh[tid] = vv[tid];
  __syncthreads();

  // hWa[j] + ba[j]  (first 256 cols of Wa act on hidden) — f32 weights
  {
    float acc = 0.f;
    const float* wr = Wa + (size_t)tid * 768;
    for (int k4 = 0; k4 < 256; k4 += 4) {
      float4 w4 = *(const float4*)(wr + k4);
      acc += sh[k4] * w4.x + sh[k4 + 1] * w4.y + sh[k4 + 2] * w4.z + sh[k4 + 3] * w4.w;
    }
    hb[tid] = clampf(acc + ba[tid], 64.f);
  }
  __syncthreads();

  // energies: wave w handles s = w, w+4, ...
  int wv = tid >> 6, ln = tid & 63;
  for (int s = wv; s < 128; s += 4) {
    const float* Er = g_EWA + ((size_t)b * 128 + s) * 256;
    float part = 0.f;
#pragma unroll
    for (int jj = 0; jj < 4; ++jj) {
      int j = ln + 64 * jj;
      part += tanh_f(hb[j] + Er[j]) * vsh[j];
    }
    part += __shfl_down(part, 32);
    part += __shfl_down(part, 16);
    part += __shfl_down(part, 8);
    part += __shfl_down(part, 4);
    part += __shfl_down(part, 2);
    part += __shfl_down(part, 1);
    if (ln == 0) es[s] = clampf(part, 512.f);
  }
  __syncthreads();

  // softmax over s
  red[tid] = (tid < 128) ? es[tid] : -3.4e38f;
  __syncthreads();
  for (int off = 128; off; off >>= 1) { if (tid < off) red[tid] = fmaxf(red[tid], red[tid + off]); __syncthreads(); }
  float mx = red[0];
  __syncthreads();
  float pexp = (tid < 128) ? fexp2((es[tid] - mx) * 1.44269504f) : 0.f;
  red[tid] = pexp;
  __syncthreads();
  for (int off = 128; off; off >>= 1) { if (tid < off) red[tid] += red[tid + off]; __syncthreads(); }
  float inv = frcp(red[0]);
  __syncthreads();
  if (tid < 128) es[tid] = pexp * inv;
  __syncthreads();

  // context
  float c0 = 0.f, c1 = 0.f;
  for (int s = 0; s < 128; ++s) {
    const bf16* er = g_ENC + ((size_t)b * 128 + s) * 512;
    float a = es[s];
    c0 += a * b2f(er[tid]);
    c1 += a * b2f(er[tid + 256]);
  }
  c0 = clampf(c0, 16.f);
  c1 = clampf(c1, 16.f);
  g_XIN[(size_t)b * 640 + 128 + tid] = __float2bfloat16(c0);
  g_XIN[(size_t)b * 640 + 384 + tid] = __float2bfloat16(c1);
  g_HC [(size_t)b * 768 + 256 + tid] = __float2bfloat16(c0);
  g_HC [(size_t)b * 768 + 512 + tid] = __float2bfloat16(c1);
  if (tid < 128)
    g_XIN[(size_t)b * 640 + tid] = __float2bfloat16(dec_emb[(size_t)stok * 128 + tid]);
}

// ---------------------------------------------------------------------------
// g = xin @ dWih.T + db fused with cell: c=sig(i)*tanh(g); h=sig(o)*tanh(c)
// grid = 16: block bx owns u-slice [16bx,16bx+16); wave = gate.
__global__ __launch_bounds__(256) void dec_gemm_cell(const float* __restrict__ db) {
  __shared__ float gst[64 * 68];
  const int tid = threadIdx.x;
  const int wave = tid >> 6, lane = tid & 63, l15 = lane & 15, quad = lane >> 4;
  const int u0 = blockIdx.x * 16;

  f32x4 acc[4];
#pragma unroll
  for (int mt = 0; mt < 4; ++mt) acc[mt] = (f32x4){0.f, 0.f, 0.f, 0.f};

  const bf16* Brow = g_WBF + OFF_DWIH + (size_t)(wave * 256 + u0 + l15) * 640 + quad * 8;
  for (int kt = 0; kt < 20; ++kt) {
    short8 bfr = *(const short8*)(Brow + kt * 32);
#pragma unroll
    for (int mt = 0; mt < 4; ++mt) {
      short8 a = *(const short8*)(g_XIN + (size_t)(16 * mt + l15) * 640 + kt * 32 + quad * 8);
      acc[mt] = mfma16(a, bfr, acc[mt]);
    }
  }
#pragma unroll
  for (int mt = 0; mt < 4; ++mt)
#pragma unroll
    for (int r = 0; r < 4; ++r)
      gst[(16 * mt + quad * 4 + r) * 68 + wave * 16 + l15] = clampf(acc[mt][r], 64.f);
  __syncthreads();

  for (int p = tid; p < 1024; p += 256) {
    int b = p >> 4, uu = p & 15;
    int u = u0 + uu;
    float gi = gst[b * 68 + 0  + uu] + db[u];
    float gg = gst[b * 68 + 32 + uu] + db[512 + u];
    float go = gst[b * 68 + 48 + uu] + db[768 + u];
    float c = sigf(gi) * tanh_f(gg);
    float h = clampf(sigf(go) * tanh_f(c), 4.f);
    g_HID[b * 256 + u] = h;
    g_HC[(size_t)b * 768 + u] = __float2bfloat16(h);
  }
}

// ---------------------------------------------------------------------------
__global__ __launch_bounds__(256) void zero_t0(float* __restrict__ outp) {
  int idx = blockIdx.x * 256 + threadIdx.x;        // 64*10000
  int b = idx / 10000, v = idx - b * 10000;
  outp[(size_t)b * 640000 + v] = 0.f;
}

// ---------------------------------------------------------------------------
extern "C" void kernel_launch(void* const* d_in, const int* in_sizes, int n_in,
                              void* d_out, int out_size, void* d_ws, size_t ws_size,
                              hipStream_t stream) {
  (void)in_sizes; (void)n_in; (void)out_size; (void)d_ws; (void)ws_size;

  const int*   src     = (const int*)   d_in[0];
  const int*   trg     = (const int*)   d_in[1];
  const unsigned char* tfm = (const unsigned char*) d_in[2];
  const float* enc_emb = (const float*) d_in[3];
  const float* e1f_Wih = (const float*) d_in[4];
  const float* e1f_Whh = (const float*) d_in[5];
  const float* e1f_b   = (const float*) d_in[6];
  const float* e1b_Wih = (const float*) d_in[7];
  const float* e1b_Whh = (const float*) d_in[8];
  const float* e1b_b   = (const float*) d_in[9];
  const float* e2f_Wih = (const float*) d_in[10];
  const float* e2f_Whh = (const float*) d_in[11];
  const float* e2f_b   = (const float*) d_in[12];
  const float* e2b_Wih = (const float*) d_in[13];
  const float* e2b_Whh = (const float*) d_in[14];
  const float* e2b_b   = (const float*) d_in[15];
  const float* dec_emb = (const float*) d_in[16];
  const float* Wa      = (const float*) d_in[17];
  const float* ba      = (const float*) d_in[18];
  const float* vv      = (const float*) d_in[19];
  const float* dWih    = (const float*) d_in[20];
  const float* db      = (const float*) d_in[21];
  const float* Wfc     = (const float*) d_in[22];
  const float* bfc     = (const float*) d_in[23];
  float* outp = (float*) d_out;

  zero_flags<<<1, 64, 0, stream>>>();

  // ---- weight conversion f32 -> bf16 pool ----
  cvt_w<<<128,  256, 0, stream>>>(e1f_Wih, OFF_E1F_WIH, 131072);
  cvt_w<<<128,  256, 0, stream>>>(e1b_Wih, OFF_E1B_WIH, 131072);
  cvt_w<<<512,  256, 0, stream>>>(e2f_Wih, OFF_E2F_WIH, 524288);
  cvt_w<<<512,  256, 0, stream>>>(e2b_Wih, OFF_E2B_WIH, 524288);
  cvt_w<<<256,  256, 0, stream>>>(e1f_Whh, OFF_E1F_WHH, 262144);
  cvt_w<<<256,  256, 0, stream>>>(e1b_Whh, OFF_E1B_WHH, 262144);
  cvt_w<<<256,  256, 0, stream>>>(e2f_Whh, OFF_E2F_WHH, 262144);
  cvt_w<<<256,  256, 0, stream>>>(e2b_Whh, OFF_E2B_WHH, 262144);
  cvt_w<<<640,  256, 0, stream>>>(dWih,    OFF_DWIH,    655360);
  cvt_w<<<7500, 256, 0, stream>>>(Wfc,     OFF_WFC,     7680000);
  cvt_w<<<192,  256, 0, stream>>>(Wa,      OFF_WA,      196608);

  // ---- encoder ----
  embed_k<<<1024, 256, 0, stream>>>(src, enc_emb);
  gemm_x1<<<dim3(128, 16), 256, 0, stream>>>(OFF_E1F_WIH, e1f_b, 0);
  gemm_x1<<<dim3(128, 16), 256, 0, stream>>>(OFF_E1B_WIH, e1b_b, 1);
  lstm_layer<<<16, 256, 0, stream>>>(OFF_E1F_WHH, OFF_E1B_WHH, 0);
  gemm_x2<<<dim3(128, 16), 256, 0, stream>>>(OFF_E2F_WIH, e2f_b, 0);
  gemm_x2<<<dim3(128, 16), 256, 0, stream>>>(OFF_E2B_WIH, e2b_b, 1);
  lstm_layer<<<16, 256, 0, stream>>>(OFF_E2F_WHH, OFF_E2B_WHH, 1);
  gemm_ewa<<<dim3(128, 4), 256, 0, stream>>>();
  zero_t0<<<2500, 256, 0, stream>>>(outp);

  // ---- decoder ----
  for (int i = 1; i < 64; ++i) {
    attn_step<<<64, 256, 0, stream>>>(i, trg, tfm, dec_emb, Wa, ba, vv, outp);
    dec_gemm_cell<<<16, 256, 0, stream>>>(db);
    gemm_pred<<<dim3(1, 157), 256, 0, stream>>>(bfc, outp, i);
  }
}